// Round 1
// baseline (24390.909 us; speedup 1.0000x reference)
//
#include <hip/hip_runtime.h>

// LightGCN: 3 × SpMM (scatter-atomic) + fused final average.
// N = n_users + n_items = 300000 nodes, d = 64, E = 9.6M edges.

static constexpr int D   = 64;   // feature dim
static constexpr int TPE = 16;   // threads per edge (each handles float4)
static constexpr int BLK = 256;

__device__ __forceinline__ float4 ldf4(const float* p) {
    return *reinterpret_cast<const float4*>(p);
}

// Layer 1: gather directly from user/item embeddings (h0 never materialized).
__global__ __launch_bounds__(BLK)
void scatter_first(const int* __restrict__ esrc, const int* __restrict__ edst,
                   const float* __restrict__ ev,
                   const float* __restrict__ ue, const float* __restrict__ ie,
                   int n_users, float* __restrict__ y, int n_edges)
{
    long long t = (long long)blockIdx.x * BLK + threadIdx.x;
    int e = (int)(t >> 4);
    if (e >= n_edges) return;
    int lane = (int)(threadIdx.x & (TPE - 1));
    int s = esrc[e];
    int d = edst[e];
    float v = ev[e];
    const float* xrow = (s < n_users) ? (ue + (size_t)s * D)
                                      : (ie + (size_t)(s - n_users) * D);
    float4 xs = ldf4(xrow + lane * 4);
    float* yp = y + (size_t)d * D + lane * 4;
    unsafeAtomicAdd(yp + 0, v * xs.x);
    unsafeAtomicAdd(yp + 1, v * xs.y);
    unsafeAtomicAdd(yp + 2, v * xs.z);
    unsafeAtomicAdd(yp + 3, v * xs.w);
}

// Layers 2,3: gather from previous layer's output.
__global__ __launch_bounds__(BLK)
void scatter_gen(const int* __restrict__ esrc, const int* __restrict__ edst,
                 const float* __restrict__ ev, const float* __restrict__ x,
                 float* __restrict__ y, int n_edges)
{
    long long t = (long long)blockIdx.x * BLK + threadIdx.x;
    int e = (int)(t >> 4);
    if (e >= n_edges) return;
    int lane = (int)(threadIdx.x & (TPE - 1));
    int s = esrc[e];
    int d = edst[e];
    float v = ev[e];
    float4 xs = ldf4(x + (size_t)s * D + lane * 4);
    float* yp = y + (size_t)d * D + lane * 4;
    unsafeAtomicAdd(yp + 0, v * xs.x);
    unsafeAtomicAdd(yp + 1, v * xs.y);
    unsafeAtomicAdd(yp + 2, v * xs.z);
    unsafeAtomicAdd(yp + 3, v * xs.w);
}

// out = (h0 + h1 + h2 + h3) / 4, h0 read straight from the embedding inputs.
__global__ __launch_bounds__(BLK)
void combine_final(const float* __restrict__ ue, const float* __restrict__ ie,
                   const float* __restrict__ h1, const float* __restrict__ h2,
                   const float* __restrict__ h3, float* __restrict__ out,
                   long long u_elems, long long total4)
{
    long long i = (long long)blockIdx.x * BLK + threadIdx.x;
    if (i >= total4) return;
    long long idx = i * 4;   // u_elems = n_users*64 is a multiple of 4
    float4 b = (idx < u_elems) ? ldf4(ue + idx) : ldf4(ie + (idx - u_elems));
    float4 a1 = ldf4(h1 + idx);
    float4 a2 = ldf4(h2 + idx);
    float4 a3 = ldf4(h3 + idx);
    float4 r;
    r.x = (b.x + a1.x + a2.x + a3.x) * 0.25f;
    r.y = (b.y + a1.y + a2.y + a3.y) * 0.25f;
    r.z = (b.z + a1.z + a2.z + a3.z) * 0.25f;
    r.w = (b.w + a1.w + a2.w + a3.w) * 0.25f;
    *reinterpret_cast<float4*>(out + idx) = r;
}

// ---- fallback (2-buffer) variant kernels ----
__global__ __launch_bounds__(BLK)
void init_concat(const float* __restrict__ ue, const float* __restrict__ ie,
                 float* __restrict__ hc, float* __restrict__ acc,
                 long long u_elems, long long total4)
{
    long long i = (long long)blockIdx.x * BLK + threadIdx.x;
    if (i >= total4) return;
    long long idx = i * 4;
    float4 b = (idx < u_elems) ? ldf4(ue + idx) : ldf4(ie + (idx - u_elems));
    *reinterpret_cast<float4*>(hc + idx)  = b;
    *reinterpret_cast<float4*>(acc + idx) = b;
}

__global__ __launch_bounds__(BLK)
void acc_add(float* __restrict__ acc, const float* __restrict__ h,
             long long total4, float scale)
{
    long long i = (long long)blockIdx.x * BLK + threadIdx.x;
    if (i >= total4) return;
    long long idx = i * 4;
    float4 a = ldf4(acc + idx);
    float4 b = ldf4(h + idx);
    float4 r;
    r.x = (a.x + b.x) * scale;
    r.y = (a.y + b.y) * scale;
    r.z = (a.z + b.z) * scale;
    r.w = (a.w + b.w) * scale;
    *reinterpret_cast<float4*>(acc + idx) = r;
}

extern "C" void kernel_launch(void* const* d_in, const int* in_sizes, int n_in,
                              void* d_out, int out_size, void* d_ws, size_t ws_size,
                              hipStream_t stream)
{
    const float* ue  = (const float*)d_in[0];
    const float* ie  = (const float*)d_in[1];
    const int*   esrc = (const int*)d_in[2];
    const int*   edst = (const int*)d_in[3];
    const float* ev  = (const float*)d_in[4];

    const int n_users = in_sizes[0] / D;
    const int n_items = in_sizes[1] / D;
    const int n_edges = in_sizes[2];
    const long long N     = (long long)n_users + (long long)n_items;
    const long long elems = N * D;               // == out_size
    const size_t bufBytes = (size_t)elems * sizeof(float);

    const int scatterBlocks = (int)(((long long)n_edges * TPE + BLK - 1) / BLK);
    const long long total4  = elems / 4;
    const int vecBlocks     = (int)((total4 + BLK - 1) / BLK);
    const long long u_elems = (long long)n_users * D;

    float* h1 = (float*)d_ws;
    float* h2 = (float*)((char*)d_ws + bufBytes);
    float* h3 = (float*)((char*)d_ws + 2 * bufBytes);

    if (ws_size >= 3 * bufBytes) {
        // 3-buffer variant: fewest passes.
        hipMemsetAsync(h1, 0, bufBytes, stream);
        hipMemsetAsync(h2, 0, bufBytes, stream);
        hipMemsetAsync(h3, 0, bufBytes, stream);
        scatter_first<<<scatterBlocks, BLK, 0, stream>>>(esrc, edst, ev, ue, ie,
                                                         n_users, h1, n_edges);
        scatter_gen<<<scatterBlocks, BLK, 0, stream>>>(esrc, edst, ev, h1, h2, n_edges);
        scatter_gen<<<scatterBlocks, BLK, 0, stream>>>(esrc, edst, ev, h2, h3, n_edges);
        combine_final<<<vecBlocks, BLK, 0, stream>>>(ue, ie, h1, h2, h3,
                                                     (float*)d_out, u_elems, total4);
    } else if (ws_size >= 2 * bufBytes) {
        // 2-buffer fallback: acc lives in d_out, ping-pong h in ws.
        float* hc = h1;
        float* hn = h2;
        float* acc = (float*)d_out;
        init_concat<<<vecBlocks, BLK, 0, stream>>>(ue, ie, hc, acc, u_elems, total4);
        for (int l = 0; l < 3; ++l) {
            hipMemsetAsync(hn, 0, bufBytes, stream);
            scatter_gen<<<scatterBlocks, BLK, 0, stream>>>(esrc, edst, ev, hc, hn, n_edges);
            const float scale = (l == 2) ? 0.25f : 1.0f;
            acc_add<<<vecBlocks, BLK, 0, stream>>>(acc, hn, total4, scale);
            float* t = hc; hc = hn; hn = t;
        }
    }
    // (ws too small for either variant would be a harness misconfiguration)
}

// Round 2
// 2348.810 us; speedup vs baseline: 10.3844x; 10.3844x over previous
//
#include <hip/hip_runtime.h>

// LightGCN on MI355X: per-call CSR build (by dst) + 3 atomic-free gather
// layers + fused final average.
// N = 300000 nodes, D = 64, E = 9.6M edges.

static constexpr int D   = 64;
static constexpr int BLK = 256;
static constexpr int WPB = BLK / 64;   // waves (nodes) per block

__device__ __forceinline__ float4 ldf4(const float* p) {
    return *reinterpret_cast<const float4*>(p);
}

// ---------------- CSR build ----------------

__global__ __launch_bounds__(256)
void k_hist(const int* __restrict__ edst, unsigned* __restrict__ cnt, int E) {
    int e = blockIdx.x * 256 + threadIdx.x;
    if (e < E) atomicAdd(&cnt[edst[e]], 1u);
}

// Single-block exclusive scan over N counts -> off[0..N], off[N] = total.
__global__ __launch_bounds__(1024)
void k_scan(const unsigned* __restrict__ cnt, unsigned* __restrict__ off, int N) {
    __shared__ unsigned wsum[16];
    __shared__ unsigned carry_s;
    const int lane = threadIdx.x & 63;
    const int w    = threadIdx.x >> 6;
    if (threadIdx.x == 0) carry_s = 0;
    __syncthreads();
    for (int base = 0; base < N; base += 1024) {
        int i = base + (int)threadIdx.x;
        unsigned v = (i < N) ? cnt[i] : 0u;
        unsigned inc = v;
        #pragma unroll
        for (int d = 1; d < 64; d <<= 1) {
            unsigned t = __shfl_up(inc, d);
            if (lane >= d) inc += t;
        }
        if (lane == 63) wsum[w] = inc;
        __syncthreads();
        if (threadIdx.x < 16) {
            unsigned x = wsum[threadIdx.x];
            #pragma unroll
            for (int d = 1; d < 16; d <<= 1) {
                unsigned t = __shfl_up(x, d);
                if ((int)threadIdx.x >= d) x += t;
            }
            wsum[threadIdx.x] = x;
        }
        __syncthreads();
        unsigned carry = carry_s;
        unsigned woff  = (w == 0) ? 0u : wsum[w - 1];
        if (i < N) off[i] = carry + woff + inc - v;
        __syncthreads();
        if (threadIdx.x == 1023) carry_s = carry + wsum[15];
        __syncthreads();
    }
    if (threadIdx.x == 0) off[N] = carry_s;
}

__global__ __launch_bounds__(256)
void k_copy(const unsigned* __restrict__ off, unsigned* __restrict__ cur, int N) {
    int i = blockIdx.x * 256 + threadIdx.x;
    if (i < N) cur[i] = off[i];
}

// Bucket-scatter edges into dst-sorted order; pack (src, val) into 8 bytes.
__global__ __launch_bounds__(256)
void k_scatter(const int* __restrict__ esrc, const int* __restrict__ edst,
               const float* __restrict__ ev, unsigned* __restrict__ cur,
               unsigned long long* __restrict__ edges, int E) {
    int e = blockIdx.x * 256 + threadIdx.x;
    if (e >= E) return;
    unsigned p = atomicAdd(&cur[edst[e]], 1u);
    unsigned long long pk = (unsigned long long)(unsigned)esrc[e]
                          | ((unsigned long long)__float_as_uint(ev[e]) << 32);
    edges[p] = pk;
}

// ---------------- propagation ----------------

// hA = concat(ue, ie); acc = hA.
__global__ __launch_bounds__(BLK)
void k_init(const float* __restrict__ ue, const float* __restrict__ ie,
            float* __restrict__ hA, float* __restrict__ acc,
            long long u_elems, long long total4) {
    long long i = (long long)blockIdx.x * BLK + threadIdx.x;
    if (i >= total4) return;
    long long idx = i * 4;
    float4 b = (idx < u_elems) ? ldf4(ue + idx) : ldf4(ie + (idx - u_elems));
    *reinterpret_cast<float4*>(hA + idx)  = b;
    *reinterpret_cast<float4*>(acc + idx) = b;
}

// One wave per dst node: hn[node] = sum val*x[src]; acc = (acc + hn) * scale.
__global__ __launch_bounds__(BLK)
void k_gather(const unsigned* __restrict__ off,
              const unsigned long long* __restrict__ edges,
              const float* __restrict__ x, float* __restrict__ hn,
              float* __restrict__ acc, float scale, int write_h, int N) {
    __shared__ unsigned long long sh[WPB][64];
    const int w    = threadIdx.x >> 6;
    const int lane = threadIdx.x & 63;
    const int node = blockIdx.x * WPB + w;
    if (node >= N) return;
    const unsigned beg = off[node];
    const unsigned end = off[node + 1];
    float a = 0.f;
    for (unsigned base = beg; base < end; base += 64) {
        const int cnt = (int)min(64u, end - base);
        if (lane < cnt) sh[w][lane] = edges[base + lane];
        // wave-synchronous LDS use (single wave owns sh[w]); compiler inserts
        // the lgkmcnt wait between the ds_write and the ds_reads below.
        int j = 0;
        for (; j + 4 <= cnt; j += 4) {
            unsigned long long p0 = sh[w][j + 0], p1 = sh[w][j + 1];
            unsigned long long p2 = sh[w][j + 2], p3 = sh[w][j + 3];
            float x0 = x[(size_t)(unsigned)p0 * D + lane];
            float x1 = x[(size_t)(unsigned)p1 * D + lane];
            float x2 = x[(size_t)(unsigned)p2 * D + lane];
            float x3 = x[(size_t)(unsigned)p3 * D + lane];
            a += __uint_as_float((unsigned)(p0 >> 32)) * x0;
            a += __uint_as_float((unsigned)(p1 >> 32)) * x1;
            a += __uint_as_float((unsigned)(p2 >> 32)) * x2;
            a += __uint_as_float((unsigned)(p3 >> 32)) * x3;
        }
        for (; j < cnt; ++j) {
            unsigned long long p = sh[w][j];
            a += __uint_as_float((unsigned)(p >> 32)) * x[(size_t)(unsigned)p * D + lane];
        }
    }
    size_t o = (size_t)node * D + lane;
    if (write_h) hn[o] = a;
    acc[o] = (acc[o] + a) * scale;
}

// ---------------- fallback (round-1 atomic path) ----------------

__global__ __launch_bounds__(BLK)
void scatter_first(const int* __restrict__ esrc, const int* __restrict__ edst,
                   const float* __restrict__ ev,
                   const float* __restrict__ ue, const float* __restrict__ ie,
                   int n_users, float* __restrict__ y, int n_edges) {
    long long t = (long long)blockIdx.x * BLK + threadIdx.x;
    int e = (int)(t >> 4);
    if (e >= n_edges) return;
    int lane = (int)(threadIdx.x & 15);
    int s = esrc[e];
    int d = edst[e];
    float v = ev[e];
    const float* xrow = (s < n_users) ? (ue + (size_t)s * D)
                                      : (ie + (size_t)(s - n_users) * D);
    float4 xs = ldf4(xrow + lane * 4);
    float* yp = y + (size_t)d * D + lane * 4;
    unsafeAtomicAdd(yp + 0, v * xs.x);
    unsafeAtomicAdd(yp + 1, v * xs.y);
    unsafeAtomicAdd(yp + 2, v * xs.z);
    unsafeAtomicAdd(yp + 3, v * xs.w);
}

__global__ __launch_bounds__(BLK)
void scatter_gen(const int* __restrict__ esrc, const int* __restrict__ edst,
                 const float* __restrict__ ev, const float* __restrict__ x,
                 float* __restrict__ y, int n_edges) {
    long long t = (long long)blockIdx.x * BLK + threadIdx.x;
    int e = (int)(t >> 4);
    if (e >= n_edges) return;
    int lane = (int)(threadIdx.x & 15);
    int s = esrc[e];
    int d = edst[e];
    float v = ev[e];
    float4 xs = ldf4(x + (size_t)s * D + lane * 4);
    float* yp = y + (size_t)d * D + lane * 4;
    unsafeAtomicAdd(yp + 0, v * xs.x);
    unsafeAtomicAdd(yp + 1, v * xs.y);
    unsafeAtomicAdd(yp + 2, v * xs.z);
    unsafeAtomicAdd(yp + 3, v * xs.w);
}

__global__ __launch_bounds__(BLK)
void combine_final(const float* __restrict__ ue, const float* __restrict__ ie,
                   const float* __restrict__ h1, const float* __restrict__ h2,
                   const float* __restrict__ h3, float* __restrict__ out,
                   long long u_elems, long long total4) {
    long long i = (long long)blockIdx.x * BLK + threadIdx.x;
    if (i >= total4) return;
    long long idx = i * 4;
    float4 b = (idx < u_elems) ? ldf4(ue + idx) : ldf4(ie + (idx - u_elems));
    float4 a1 = ldf4(h1 + idx);
    float4 a2 = ldf4(h2 + idx);
    float4 a3 = ldf4(h3 + idx);
    float4 r;
    r.x = (b.x + a1.x + a2.x + a3.x) * 0.25f;
    r.y = (b.y + a1.y + a2.y + a3.y) * 0.25f;
    r.z = (b.z + a1.z + a2.z + a3.z) * 0.25f;
    r.w = (b.w + a1.w + a2.w + a3.w) * 0.25f;
    *reinterpret_cast<float4*>(out + idx) = r;
}

// ---------------- launch ----------------

extern "C" void kernel_launch(void* const* d_in, const int* in_sizes, int n_in,
                              void* d_out, int out_size, void* d_ws, size_t ws_size,
                              hipStream_t stream) {
    const float* ue   = (const float*)d_in[0];
    const float* ie   = (const float*)d_in[1];
    const int*   esrc = (const int*)d_in[2];
    const int*   edst = (const int*)d_in[3];
    const float* ev   = (const float*)d_in[4];

    const int n_users = in_sizes[0] / D;
    const int n_items = in_sizes[1] / D;
    const int E       = in_sizes[2];
    const int N       = n_users + n_items;
    const long long elems = (long long)N * D;
    const size_t bufBytes = (size_t)elems * sizeof(float);

    const long long total4  = elems / 4;
    const int vecBlocks     = (int)((total4 + BLK - 1) / BLK);
    const long long u_elems = (long long)n_users * D;
    float* out = (float*)d_out;

    // CSR-path workspace layout
    char* p = (char*)d_ws;
    float*              hA    = (float*)p;                 p += bufBytes;
    float*              hB    = (float*)p;                 p += bufBytes;
    unsigned long long* edges = (unsigned long long*)p;    p += (size_t)E * 8;
    unsigned*           offp  = (unsigned*)p;              p += ((size_t)N + 1) * 4;
    unsigned*           cur   = (unsigned*)p;              p += (size_t)N * 4;
    const size_t need = (size_t)(p - (char*)d_ws);

    if (ws_size >= need) {
        const int eBlocks = (E + 255) / 256;
        const int nBlocks = (N + 255) / 256;
        const int gBlocks = (N + WPB - 1) / WPB;

        // CSR build (by dst)
        hipMemsetAsync(cur, 0, (size_t)N * 4, stream);
        k_hist<<<eBlocks, 256, 0, stream>>>(edst, cur, E);
        k_scan<<<1, 1024, 0, stream>>>(cur, offp, N);
        k_copy<<<nBlocks, 256, 0, stream>>>(offp, cur, N);
        k_scatter<<<eBlocks, 256, 0, stream>>>(esrc, edst, ev, cur, edges, E);

        // h0 + fused accumulation
        k_init<<<vecBlocks, BLK, 0, stream>>>(ue, ie, hA, out, u_elems, total4);
        k_gather<<<gBlocks, BLK, 0, stream>>>(offp, edges, hA, hB, out, 1.0f, 1, N);
        k_gather<<<gBlocks, BLK, 0, stream>>>(offp, edges, hB, hA, out, 1.0f, 1, N);
        k_gather<<<gBlocks, BLK, 0, stream>>>(offp, edges, hA, hB, out, 0.25f, 0, N);
    } else {
        // fallback: round-1 atomic path (needs 3 * bufBytes)
        float* h1 = (float*)d_ws;
        float* h2 = (float*)((char*)d_ws + bufBytes);
        float* h3 = (float*)((char*)d_ws + 2 * bufBytes);
        const int scatterBlocks = (int)(((long long)E * 16 + BLK - 1) / BLK);
        hipMemsetAsync(h1, 0, bufBytes, stream);
        hipMemsetAsync(h2, 0, bufBytes, stream);
        hipMemsetAsync(h3, 0, bufBytes, stream);
        scatter_first<<<scatterBlocks, BLK, 0, stream>>>(esrc, edst, ev, ue, ie,
                                                         n_users, h1, E);
        scatter_gen<<<scatterBlocks, BLK, 0, stream>>>(esrc, edst, ev, h1, h2, E);
        scatter_gen<<<scatterBlocks, BLK, 0, stream>>>(esrc, edst, ev, h2, h3, E);
        combine_final<<<vecBlocks, BLK, 0, stream>>>(ue, ie, h1, h2, h3,
                                                     out, u_elems, total4);
    }
}

// Round 4
// 1564.810 us; speedup vs baseline: 15.5871x; 1.5010x over previous
//
#include <hip/hip_runtime.h>

// LightGCN on MI355X. Atomic-free CSR build:
//   p_hist     : per-chunk LDS histogram over 586 coarse buckets (dst>>9)
//   p_reduce / k_scan / p_scanapply : 3-pass exclusive scan of the
//                bucket-major (bucket, chunk) count matrix
//   p_part     : rank-scatter edges into coarse buckets (LDS cursors only)
//   p_bsort    : per-bucket LDS counting sort -> exact dst-sorted edges + CSR off[]
// then 3 atomic-free gather layers (h3 straight into d_out) + in-place combine.

static constexpr int D     = 64;
static constexpr int BLK   = 256;
static constexpr int WPB   = BLK / 64;   // waves (nodes) per gather block
static constexpr int CHUNK = 16384;      // edges per partition chunk
static constexpr int NBK   = 512;        // nodes per bucket (pow2: dst>>9)
static constexpr int MAXNB = 1024;       // max buckets supported (N <= 524288)

typedef unsigned long long u64;

__device__ __forceinline__ float4 ldf4(const float* p) {
    return *reinterpret_cast<const float4*>(p);
}

// ---- pass A: per-chunk histogram over coarse buckets ----
__global__ __launch_bounds__(256)
void p_hist(const int* __restrict__ edst, unsigned* __restrict__ cnt,
            int E, int NB, int nchunk) {
    __shared__ unsigned h[MAXNB];
    const int c = blockIdx.x;
    for (int j = threadIdx.x; j < NB; j += 256) h[j] = 0u;
    __syncthreads();
    const long long base = (long long)c * CHUNK;
    const int lim = (int)min((long long)CHUNK, (long long)E - base);
    for (int i = threadIdx.x; i < lim; i += 256)
        atomicAdd(&h[(unsigned)edst[base + i] >> 9], 1u);
    __syncthreads();
    for (int j = threadIdx.x; j < NB; j += 256)
        cnt[(size_t)j * nchunk + c] = h[j];
}

// ---- scan pass 1: per-1024-block reduce ----
__global__ __launch_bounds__(1024)
void p_reduce(const unsigned* __restrict__ cnt, unsigned* __restrict__ bsum, int M) {
    __shared__ unsigned wsum[16];
    int i = blockIdx.x * 1024 + threadIdx.x;
    unsigned v = (i < M) ? cnt[i] : 0u;
    #pragma unroll
    for (int d = 1; d < 64; d <<= 1) v += __shfl_xor(v, d);
    if ((threadIdx.x & 63) == 0) wsum[threadIdx.x >> 6] = v;
    __syncthreads();
    if (threadIdx.x < 16) {
        unsigned x = wsum[threadIdx.x];
        #pragma unroll
        for (int d = 1; d < 16; d <<= 1) x += __shfl_xor(x, d);
        if (threadIdx.x == 0) bsum[blockIdx.x] = x;
    }
}

// ---- scan pass 2: general single-block exclusive scan (small arrays) ----
__global__ __launch_bounds__(1024)
void k_scan(const unsigned* __restrict__ cnt, unsigned* __restrict__ off, int N) {
    __shared__ unsigned wsum[16];
    __shared__ unsigned carry_s;
    const int lane = threadIdx.x & 63;
    const int w    = threadIdx.x >> 6;
    if (threadIdx.x == 0) carry_s = 0;
    __syncthreads();
    for (int base = 0; base < N; base += 1024) {
        int i = base + (int)threadIdx.x;
        unsigned v = (i < N) ? cnt[i] : 0u;
        unsigned inc = v;
        #pragma unroll
        for (int d = 1; d < 64; d <<= 1) {
            unsigned t = __shfl_up(inc, d);
            if (lane >= d) inc += t;
        }
        if (lane == 63) wsum[w] = inc;
        __syncthreads();
        if (threadIdx.x < 16) {
            unsigned x = wsum[threadIdx.x];
            #pragma unroll
            for (int d = 1; d < 16; d <<= 1) {
                unsigned t = __shfl_up(x, d);
                if ((int)threadIdx.x >= d) x += t;
            }
            wsum[threadIdx.x] = x;
        }
        __syncthreads();
        unsigned carry = carry_s;
        unsigned woff  = (w == 0) ? 0u : wsum[w - 1];
        if (i < N) off[i] = carry + woff + inc - v;
        __syncthreads();
        if (threadIdx.x == 1023) carry_s = carry + wsum[15];
        __syncthreads();
    }
    if (threadIdx.x == 0) off[N] = carry_s;
}

// ---- scan pass 3: block exclusive scan + block base, in place ----
__global__ __launch_bounds__(1024)
void p_scanapply(unsigned* __restrict__ cnt, const unsigned* __restrict__ bsumX, int M) {
    __shared__ unsigned wsum[16];
    const int lane = threadIdx.x & 63;
    const int w    = threadIdx.x >> 6;
    int i = blockIdx.x * 1024 + threadIdx.x;
    unsigned v = (i < M) ? cnt[i] : 0u;
    unsigned inc = v;
    #pragma unroll
    for (int d = 1; d < 64; d <<= 1) {
        unsigned t = __shfl_up(inc, d);
        if (lane >= d) inc += t;
    }
    if (lane == 63) wsum[w] = inc;
    __syncthreads();
    if (threadIdx.x < 16) {
        unsigned x = wsum[threadIdx.x];
        #pragma unroll
        for (int d = 1; d < 16; d <<= 1) {
            unsigned t = __shfl_up(x, d);
            if ((int)threadIdx.x >= d) x += t;
        }
        wsum[threadIdx.x] = x;
    }
    __syncthreads();
    unsigned excl = inc - v + ((w == 0) ? 0u : wsum[w - 1]) + bsumX[blockIdx.x];
    if (i < M) cnt[i] = excl;
}

// ---- pass C: rank-scatter into coarse buckets (LDS cursors, no global atomics) ----
__global__ __launch_bounds__(256)
void p_part(const int* __restrict__ esrc, const int* __restrict__ edst,
            const float* __restrict__ ev, const unsigned* __restrict__ cnt,
            u64* __restrict__ tmp, int E, int NB, int nchunk) {
    __shared__ unsigned cur[MAXNB];
    const int c = blockIdx.x;
    for (int j = threadIdx.x; j < NB; j += 256)
        cur[j] = cnt[(size_t)j * nchunk + c];
    __syncthreads();
    const long long base = (long long)c * CHUNK;
    const int lim = (int)min((long long)CHUNK, (long long)E - base);
    for (int i = threadIdx.x; i < lim; i += 256) {
        long long e = base + i;
        unsigned s  = (unsigned)esrc[e];
        unsigned d  = (unsigned)edst[e];
        unsigned vb = __float_as_uint(ev[e]);
        unsigned b  = d >> 9;
        unsigned dl = d & (NBK - 1);
        unsigned pos = atomicAdd(&cur[b], 1u);   // LDS atomic
        tmp[pos] = ((u64)((dl << 19) | s) << 32) | vb;  // [dl:9][src:19][val:32]
    }
}

// ---- pass D: per-bucket LDS counting sort -> final edges + CSR off[] ----
__global__ __launch_bounds__(256)
void p_bsort(const u64* __restrict__ tmp, const unsigned* __restrict__ cnt,
             u64* __restrict__ fin, unsigned* __restrict__ off,
             int E, int N, int NB, int nchunk) {
    __shared__ unsigned c2[NBK];
    __shared__ unsigned o2[NBK];
    __shared__ unsigned ws4[4];
    const int b = blockIdx.x, tid = threadIdx.x;
    const int lane = tid & 63, w = tid >> 6;
    const unsigned base = cnt[(size_t)b * nchunk];
    const unsigned end  = (b + 1 < NB) ? cnt[(size_t)(b + 1) * nchunk] : (unsigned)E;
    c2[tid] = 0u; c2[tid + 256] = 0u;
    __syncthreads();
    for (unsigned i = base + tid; i < end; i += 256) {
        unsigned dl = (unsigned)(tmp[i] >> 51) & (NBK - 1);
        atomicAdd(&c2[dl], 1u);
    }
    __syncthreads();
    // exclusive scan of 512 counters (two rounds of 256)
    unsigned v = c2[tid], inc = v;
    #pragma unroll
    for (int d = 1; d < 64; d <<= 1) { unsigned t = __shfl_up(inc, d); if (lane >= d) inc += t; }
    if (lane == 63) ws4[w] = inc;
    __syncthreads();
    if (tid < 4) {
        unsigned x = ws4[tid];
        #pragma unroll
        for (int d = 1; d < 4; d <<= 1) { unsigned t = __shfl_up(x, d); if (tid >= d) x += t; }
        ws4[tid] = x;
    }
    __syncthreads();
    unsigned exclA = inc - v + ((w == 0) ? 0u : ws4[w - 1]);
    unsigned totA  = ws4[3];
    __syncthreads();
    unsigned v2 = c2[tid + 256], inc2 = v2;
    #pragma unroll
    for (int d = 1; d < 64; d <<= 1) { unsigned t = __shfl_up(inc2, d); if (lane >= d) inc2 += t; }
    if (lane == 63) ws4[w] = inc2;
    __syncthreads();
    if (tid < 4) {
        unsigned x = ws4[tid];
        #pragma unroll
        for (int d = 1; d < 4; d <<= 1) { unsigned t = __shfl_up(x, d); if (tid >= d) x += t; }
        ws4[tid] = x;
    }
    __syncthreads();
    unsigned exclB = inc2 - v2 + ((w == 0) ? 0u : ws4[w - 1]) + totA;
    o2[tid] = base + exclA;
    o2[tid + 256] = base + exclB;
    __syncthreads();
    // CSR offsets
    int n0 = b * NBK + tid;
    int n1 = n0 + 256;
    if (n0 < N) off[n0] = o2[tid];
    if (n1 < N) off[n1] = o2[tid + 256];
    if (b == 0 && tid == 0) off[N] = (unsigned)E;
    __syncthreads();
    // rank + scatter to final (writes stay inside this bucket's ~150KB region)
    for (unsigned i = base + tid; i < end; i += 256) {
        u64 pk = tmp[i];
        unsigned dl  = (unsigned)(pk >> 51) & (NBK - 1);
        unsigned src = (unsigned)(pk >> 32) & 0x7FFFFu;
        unsigned vb  = (unsigned)pk;
        unsigned pos = atomicAdd(&o2[dl], 1u);  // LDS atomic
        fin[pos] = (u64)src | ((u64)vb << 32);
    }
}

// ---- gather layers (one wave per dst node, atomic-free) ----
#define GATHER_BODY(XROW_EXPR)                                                  \
    __shared__ u64 sh[WPB][64];                                                 \
    const int w    = threadIdx.x >> 6;                                          \
    const int lane = threadIdx.x & 63;                                          \
    const int node = blockIdx.x * WPB + w;                                      \
    if (node >= N) return;                                                      \
    const unsigned beg = off[node];                                             \
    const unsigned end = off[node + 1];                                         \
    float a = 0.f;                                                              \
    for (unsigned base = beg; base < end; base += 64) {                         \
        const int cnt = (int)min(64u, end - base);                              \
        if (lane < cnt) sh[w][lane] = edges[base + lane];                       \
        int j = 0;                                                              \
        for (; j + 8 <= cnt; j += 8) {                                          \
            float xs[8]; unsigned vb[8];                                        \
            _Pragma("unroll")                                                   \
            for (int q = 0; q < 8; ++q) {                                       \
                u64 p = sh[w][j + q];                                           \
                unsigned s = (unsigned)p;                                       \
                vb[q] = (unsigned)(p >> 32);                                    \
                xs[q] = (XROW_EXPR)[lane];                                      \
            }                                                                   \
            _Pragma("unroll")                                                   \
            for (int q = 0; q < 8; ++q) a += __uint_as_float(vb[q]) * xs[q];    \
        }                                                                       \
        for (; j < cnt; ++j) {                                                  \
            u64 p = sh[w][j];                                                   \
            unsigned s = (unsigned)p;                                           \
            a += __uint_as_float((unsigned)(p >> 32)) * (XROW_EXPR)[lane];      \
        }                                                                       \
    }                                                                           \
    out[(size_t)node * D + lane] = a;

__global__ __launch_bounds__(BLK)
void g_first(const unsigned* __restrict__ off, const u64* __restrict__ edges,
             const float* __restrict__ ue, const float* __restrict__ ie,
             int n_users, float* __restrict__ out, int N) {
    GATHER_BODY(((int)s < n_users ? ue + (size_t)s * D : ie + (size_t)(s - n_users) * D))
}

__global__ __launch_bounds__(BLK)
void g_gen(const unsigned* __restrict__ off, const u64* __restrict__ edges,
           const float* __restrict__ x, float* __restrict__ out, int N) {
    GATHER_BODY((x + (size_t)s * D))
}

// ---- out = (h0 + h1 + h2 + out)/4, in place (out holds h3) ----
__global__ __launch_bounds__(BLK)
void k_combine(const float* __restrict__ ue, const float* __restrict__ ie,
               const float* __restrict__ h1, const float* __restrict__ h2,
               float* __restrict__ out, long long u_elems, long long total4) {
    long long i = (long long)blockIdx.x * BLK + threadIdx.x;
    if (i >= total4) return;
    long long idx = i * 4;
    float4 b  = (idx < u_elems) ? ldf4(ue + idx) : ldf4(ie + (idx - u_elems));
    float4 a1 = ldf4(h1 + idx);
    float4 a2 = ldf4(h2 + idx);
    float4 a3 = ldf4(out + idx);
    float4 r;
    r.x = (b.x + a1.x + a2.x + a3.x) * 0.25f;
    r.y = (b.y + a1.y + a2.y + a3.y) * 0.25f;
    r.z = (b.z + a1.z + a2.z + a3.z) * 0.25f;
    r.w = (b.w + a1.w + a2.w + a3.w) * 0.25f;
    *reinterpret_cast<float4*>(out + idx) = r;
}

// ---- fallback: round-1 atomic push path ----
__global__ __launch_bounds__(BLK)
void scatter_first(const int* __restrict__ esrc, const int* __restrict__ edst,
                   const float* __restrict__ ev,
                   const float* __restrict__ ue, const float* __restrict__ ie,
                   int n_users, float* __restrict__ y, int n_edges) {
    long long t = (long long)blockIdx.x * BLK + threadIdx.x;
    int e = (int)(t >> 4);
    if (e >= n_edges) return;
    int lane = (int)(threadIdx.x & 15);
    int s = esrc[e]; int d = edst[e]; float v = ev[e];
    const float* xrow = (s < n_users) ? (ue + (size_t)s * D)
                                      : (ie + (size_t)(s - n_users) * D);
    float4 xs = ldf4(xrow + lane * 4);
    float* yp = y + (size_t)d * D + lane * 4;
    unsafeAtomicAdd(yp + 0, v * xs.x);
    unsafeAtomicAdd(yp + 1, v * xs.y);
    unsafeAtomicAdd(yp + 2, v * xs.z);
    unsafeAtomicAdd(yp + 3, v * xs.w);
}

__global__ __launch_bounds__(BLK)
void scatter_gen(const int* __restrict__ esrc, const int* __restrict__ edst,
                 const float* __restrict__ ev, const float* __restrict__ x,
                 float* __restrict__ y, int n_edges) {
    long long t = (long long)blockIdx.x * BLK + threadIdx.x;
    int e = (int)(t >> 4);
    if (e >= n_edges) return;
    int lane = (int)(threadIdx.x & 15);
    int s = esrc[e]; int d = edst[e]; float v = ev[e];
    float4 xs = ldf4(x + (size_t)s * D + lane * 4);
    float* yp = y + (size_t)d * D + lane * 4;
    unsafeAtomicAdd(yp + 0, v * xs.x);
    unsafeAtomicAdd(yp + 1, v * xs.y);
    unsafeAtomicAdd(yp + 2, v * xs.z);
    unsafeAtomicAdd(yp + 3, v * xs.w);
}

__global__ __launch_bounds__(BLK)
void combine4(const float* __restrict__ ue, const float* __restrict__ ie,
              const float* __restrict__ h1, const float* __restrict__ h2,
              const float* __restrict__ h3, float* __restrict__ out,
              long long u_elems, long long total4) {
    long long i = (long long)blockIdx.x * BLK + threadIdx.x;
    if (i >= total4) return;
    long long idx = i * 4;
    float4 b  = (idx < u_elems) ? ldf4(ue + idx) : ldf4(ie + (idx - u_elems));
    float4 a1 = ldf4(h1 + idx);
    float4 a2 = ldf4(h2 + idx);
    float4 a3 = ldf4(h3 + idx);
    float4 r;
    r.x = (b.x + a1.x + a2.x + a3.x) * 0.25f;
    r.y = (b.y + a1.y + a2.y + a3.y) * 0.25f;
    r.z = (b.z + a1.z + a2.z + a3.z) * 0.25f;
    r.w = (b.w + a1.w + a2.w + a3.w) * 0.25f;
    *reinterpret_cast<float4*>(out + idx) = r;
}

// ---- launch ----
extern "C" void kernel_launch(void* const* d_in, const int* in_sizes, int n_in,
                              void* d_out, int out_size, void* d_ws, size_t ws_size,
                              hipStream_t stream) {
    const float* ue   = (const float*)d_in[0];
    const float* ie   = (const float*)d_in[1];
    const int*   esrc = (const int*)d_in[2];
    const int*   edst = (const int*)d_in[3];
    const float* ev   = (const float*)d_in[4];

    const int n_users = in_sizes[0] / D;
    const int n_items = in_sizes[1] / D;
    const int E       = in_sizes[2];
    const int N       = n_users + n_items;
    const long long elems = (long long)N * D;
    const size_t bufBytes = (size_t)elems * sizeof(float);

    const int NB     = (N + NBK - 1) / NBK;       // 586
    const int nchunk = (E + CHUNK - 1) / CHUNK;   // 586
    const int M      = NB * nchunk;
    const int nb1    = (M + 1023) / 1024;

    const long long total4  = elems / 4;
    const int vecBlocks     = (int)((total4 + BLK - 1) / BLK);
    const long long u_elems = (long long)n_users * D;
    const int gBlocks       = (N + WPB - 1) / WPB;
    float* out = (float*)d_out;

    // workspace layout (tmp aliases hA: tmp dead before hA first written)
    const size_t tmpBytes = (size_t)E * 8;
    const size_t hASize   = bufBytes > tmpBytes ? bufBytes : tmpBytes;
    char* p = (char*)d_ws;
    float*    hA    = (float*)p;    u64* tmp = (u64*)p;   p += hASize;
    float*    hB    = (float*)p;                          p += bufBytes;
    u64*      fin   = (u64*)p;                            p += tmpBytes;
    unsigned* cnt   = (unsigned*)p;                       p += (size_t)M * 4;
    unsigned* off   = (unsigned*)p;                       p += ((size_t)N + 1) * 4;
    unsigned* bsum  = (unsigned*)p;                       p += (size_t)nb1 * 4;
    unsigned* bsumX = (unsigned*)p;                       p += ((size_t)nb1 + 1) * 4;
    const size_t need = (size_t)(p - (char*)d_ws);

    if (ws_size >= need && NB <= MAXNB) {
        // CSR build, no global atomics
        p_hist<<<nchunk, 256, 0, stream>>>(edst, cnt, E, NB, nchunk);
        p_reduce<<<nb1, 1024, 0, stream>>>(cnt, bsum, M);
        k_scan<<<1, 1024, 0, stream>>>(bsum, bsumX, nb1);
        p_scanapply<<<nb1, 1024, 0, stream>>>(cnt, bsumX, M);
        p_part<<<nchunk, 256, 0, stream>>>(esrc, edst, ev, cnt, tmp, E, NB, nchunk);
        p_bsort<<<NB, 256, 0, stream>>>(tmp, cnt, fin, off, E, N, NB, nchunk);
        // propagation: h1 -> hA, h2 -> hB, h3 -> out, then in-place combine
        g_first<<<gBlocks, BLK, 0, stream>>>(off, fin, ue, ie, n_users, hA, N);
        g_gen<<<gBlocks, BLK, 0, stream>>>(off, fin, hA, hB, N);
        g_gen<<<gBlocks, BLK, 0, stream>>>(off, fin, hB, out, N);
        k_combine<<<vecBlocks, BLK, 0, stream>>>(ue, ie, hA, hB, out, u_elems, total4);
    } else {
        // fallback: atomic push path (3 * bufBytes)
        float* h1 = (float*)d_ws;
        float* h2 = (float*)((char*)d_ws + bufBytes);
        float* h3 = (float*)((char*)d_ws + 2 * bufBytes);
        const int scatterBlocks = (int)(((long long)E * 16 + BLK - 1) / BLK);
        hipMemsetAsync(h1, 0, bufBytes, stream);
        hipMemsetAsync(h2, 0, bufBytes, stream);
        hipMemsetAsync(h3, 0, bufBytes, stream);
        scatter_first<<<scatterBlocks, BLK, 0, stream>>>(esrc, edst, ev, ue, ie,
                                                         n_users, h1, E);
        scatter_gen<<<scatterBlocks, BLK, 0, stream>>>(esrc, edst, ev, h1, h2, E);
        scatter_gen<<<scatterBlocks, BLK, 0, stream>>>(esrc, edst, ev, h2, h3, E);
        combine4<<<vecBlocks, BLK, 0, stream>>>(ue, ie, h1, h2, h3, out,
                                                u_elems, total4);
    }
}

// Round 6
// 999.282 us; speedup vs baseline: 24.4084x; 1.5659x over previous
//
#include <hip/hip_runtime.h>

// LightGCN on MI355X, round 5 (resubmit — round-5 bench was an infra failure).
// CSR build (atomic-free, two-level counting sort) + bf16 feature storage:
//   p_hist / p_reduce / k_scan / p_scanapply / p_part / p_bsort
//   k_cvt : concat(ue,ie) -> bf16 x0 (aliases tmp, runs after p_bsort)
//   g_gather<0> x0 -> h1b (bf16), h1b -> h2b (bf16)
//   g_gather<1> h2b -> out, fused (h0_f32 + h1 + h2 + h3)/4
// Gather: one wave per dst node, 4 edges/iteration (16 lanes x ushort4 each),
// cross-quarter shfl_xor reduce.

static constexpr int D     = 64;
static constexpr int BLK   = 256;
static constexpr int WPB   = BLK / 64;   // waves (nodes) per gather block
static constexpr int CHUNK = 16384;      // edges per partition chunk
static constexpr int NBK   = 512;        // nodes per bucket (dst>>9)
static constexpr int MAXNB = 1024;

typedef unsigned long long u64;
typedef unsigned short u16;

__device__ __forceinline__ float4 ldf4(const float* p) {
    return *reinterpret_cast<const float4*>(p);
}
__device__ __forceinline__ u16 f2b(float f) {          // f32 -> bf16 (RNE)
    unsigned u = __float_as_uint(f);
    return (u16)((u + 0x7FFFu + ((u >> 16) & 1u)) >> 16);
}
__device__ __forceinline__ float b2f(u16 h) {
    return __uint_as_float((unsigned)h << 16);
}

// ---- pass A: per-chunk histogram over coarse buckets ----
__global__ __launch_bounds__(256)
void p_hist(const int* __restrict__ edst, unsigned* __restrict__ cnt,
            int E, int NB, int nchunk) {
    __shared__ unsigned h[MAXNB];
    const int c = blockIdx.x;
    for (int j = threadIdx.x; j < NB; j += 256) h[j] = 0u;
    __syncthreads();
    const long long base = (long long)c * CHUNK;
    const int lim = (int)min((long long)CHUNK, (long long)E - base);
    const int nv = lim >> 2;
    const int4* d4 = (const int4*)(edst + base);
    for (int i = threadIdx.x; i < nv; i += 256) {
        int4 d = d4[i];
        atomicAdd(&h[(unsigned)d.x >> 9], 1u);
        atomicAdd(&h[(unsigned)d.y >> 9], 1u);
        atomicAdd(&h[(unsigned)d.z >> 9], 1u);
        atomicAdd(&h[(unsigned)d.w >> 9], 1u);
    }
    for (int i = (nv << 2) + threadIdx.x; i < lim; i += 256)
        atomicAdd(&h[(unsigned)edst[base + i] >> 9], 1u);
    __syncthreads();
    for (int j = threadIdx.x; j < NB; j += 256)
        cnt[(size_t)j * nchunk + c] = h[j];
}

// ---- scan pass 1: per-1024-block reduce ----
__global__ __launch_bounds__(1024)
void p_reduce(const unsigned* __restrict__ cnt, unsigned* __restrict__ bsum, int M) {
    __shared__ unsigned wsum[16];
    int i = blockIdx.x * 1024 + threadIdx.x;
    unsigned v = (i < M) ? cnt[i] : 0u;
    #pragma unroll
    for (int d = 1; d < 64; d <<= 1) v += __shfl_xor(v, d);
    if ((threadIdx.x & 63) == 0) wsum[threadIdx.x >> 6] = v;
    __syncthreads();
    if (threadIdx.x < 16) {
        unsigned x = wsum[threadIdx.x];
        #pragma unroll
        for (int d = 1; d < 16; d <<= 1) x += __shfl_xor(x, d);
        if (threadIdx.x == 0) bsum[blockIdx.x] = x;
    }
}

// ---- scan pass 2: single-block exclusive scan (small arrays) ----
__global__ __launch_bounds__(1024)
void k_scan(const unsigned* __restrict__ cnt, unsigned* __restrict__ off, int N) {
    __shared__ unsigned wsum[16];
    __shared__ unsigned carry_s;
    const int lane = threadIdx.x & 63;
    const int w    = threadIdx.x >> 6;
    if (threadIdx.x == 0) carry_s = 0;
    __syncthreads();
    for (int base = 0; base < N; base += 1024) {
        int i = base + (int)threadIdx.x;
        unsigned v = (i < N) ? cnt[i] : 0u;
        unsigned inc = v;
        #pragma unroll
        for (int d = 1; d < 64; d <<= 1) {
            unsigned t = __shfl_up(inc, d);
            if (lane >= d) inc += t;
        }
        if (lane == 63) wsum[w] = inc;
        __syncthreads();
        if (threadIdx.x < 16) {
            unsigned x = wsum[threadIdx.x];
            #pragma unroll
            for (int d = 1; d < 16; d <<= 1) {
                unsigned t = __shfl_up(x, d);
                if ((int)threadIdx.x >= d) x += t;
            }
            wsum[threadIdx.x] = x;
        }
        __syncthreads();
        unsigned carry = carry_s;
        unsigned woff  = (w == 0) ? 0u : wsum[w - 1];
        if (i < N) off[i] = carry + woff + inc - v;
        __syncthreads();
        if (threadIdx.x == 1023) carry_s = carry + wsum[15];
        __syncthreads();
    }
    if (threadIdx.x == 0) off[N] = carry_s;
}

// ---- scan pass 3: block exclusive scan + block base, in place ----
__global__ __launch_bounds__(1024)
void p_scanapply(unsigned* __restrict__ cnt, const unsigned* __restrict__ bsumX, int M) {
    __shared__ unsigned wsum[16];
    const int lane = threadIdx.x & 63;
    const int w    = threadIdx.x >> 6;
    int i = blockIdx.x * 1024 + threadIdx.x;
    unsigned v = (i < M) ? cnt[i] : 0u;
    unsigned inc = v;
    #pragma unroll
    for (int d = 1; d < 64; d <<= 1) {
        unsigned t = __shfl_up(inc, d);
        if (lane >= d) inc += t;
    }
    if (lane == 63) wsum[w] = inc;
    __syncthreads();
    if (threadIdx.x < 16) {
        unsigned x = wsum[threadIdx.x];
        #pragma unroll
        for (int d = 1; d < 16; d <<= 1) {
            unsigned t = __shfl_up(x, d);
            if ((int)threadIdx.x >= d) x += t;
        }
        wsum[threadIdx.x] = x;
    }
    __syncthreads();
    unsigned excl = inc - v + ((w == 0) ? 0u : wsum[w - 1]) + bsumX[blockIdx.x];
    if (i < M) cnt[i] = excl;
}

// ---- pass C: rank-scatter into coarse buckets (LDS cursors) ----
__device__ __forceinline__ void part1(unsigned s, unsigned d, float v,
                                      unsigned* cur, u64* __restrict__ tmp) {
    unsigned b  = d >> 9;
    unsigned dl = d & (NBK - 1);
    unsigned pos = atomicAdd(&cur[b], 1u);   // LDS atomic
    tmp[pos] = ((u64)((dl << 19) | s) << 32) | __float_as_uint(v);
}

__global__ __launch_bounds__(256)
void p_part(const int* __restrict__ esrc, const int* __restrict__ edst,
            const float* __restrict__ ev, const unsigned* __restrict__ cnt,
            u64* __restrict__ tmp, int E, int NB, int nchunk) {
    __shared__ unsigned cur[MAXNB];
    const int c = blockIdx.x;
    for (int j = threadIdx.x; j < NB; j += 256)
        cur[j] = cnt[(size_t)j * nchunk + c];
    __syncthreads();
    const long long base = (long long)c * CHUNK;
    const int lim = (int)min((long long)CHUNK, (long long)E - base);
    const int nv = lim >> 2;
    const int4*   s4 = (const int4*)(esrc + base);
    const int4*   d4 = (const int4*)(edst + base);
    const float4* v4 = (const float4*)(ev + base);
    for (int i = threadIdx.x; i < nv; i += 256) {
        int4 ss = s4[i]; int4 dd = d4[i]; float4 vv = v4[i];
        part1((unsigned)ss.x, (unsigned)dd.x, vv.x, cur, tmp);
        part1((unsigned)ss.y, (unsigned)dd.y, vv.y, cur, tmp);
        part1((unsigned)ss.z, (unsigned)dd.z, vv.z, cur, tmp);
        part1((unsigned)ss.w, (unsigned)dd.w, vv.w, cur, tmp);
    }
    for (int i = (nv << 2) + threadIdx.x; i < lim; i += 256)
        part1((unsigned)esrc[base + i], (unsigned)edst[base + i], ev[base + i], cur, tmp);
}

// ---- pass D: per-bucket LDS counting sort -> final edges + CSR off[] ----
__global__ __launch_bounds__(256)
void p_bsort(const u64* __restrict__ tmp, const unsigned* __restrict__ cnt,
             u64* __restrict__ fin, unsigned* __restrict__ off,
             int E, int N, int NB, int nchunk) {
    __shared__ unsigned c2[NBK];
    __shared__ unsigned o2[NBK];
    __shared__ unsigned ws4[4];
    const int b = blockIdx.x, tid = threadIdx.x;
    const int lane = tid & 63, w = tid >> 6;
    const unsigned base = cnt[(size_t)b * nchunk];
    const unsigned end  = (b + 1 < NB) ? cnt[(size_t)(b + 1) * nchunk] : (unsigned)E;
    c2[tid] = 0u; c2[tid + 256] = 0u;
    __syncthreads();
    for (unsigned i = base + tid; i < end; i += 256) {
        unsigned dl = (unsigned)(tmp[i] >> 51) & (NBK - 1);
        atomicAdd(&c2[dl], 1u);
    }
    __syncthreads();
    unsigned v = c2[tid], inc = v;
    #pragma unroll
    for (int d = 1; d < 64; d <<= 1) { unsigned t = __shfl_up(inc, d); if (lane >= d) inc += t; }
    if (lane == 63) ws4[w] = inc;
    __syncthreads();
    if (tid < 4) {
        unsigned x = ws4[tid];
        #pragma unroll
        for (int d = 1; d < 4; d <<= 1) { unsigned t = __shfl_up(x, d); if (tid >= d) x += t; }
        ws4[tid] = x;
    }
    __syncthreads();
    unsigned exclA = inc - v + ((w == 0) ? 0u : ws4[w - 1]);
    unsigned totA  = ws4[3];
    __syncthreads();
    unsigned v2 = c2[tid + 256], inc2 = v2;
    #pragma unroll
    for (int d = 1; d < 64; d <<= 1) { unsigned t = __shfl_up(inc2, d); if (lane >= d) inc2 += t; }
    if (lane == 63) ws4[w] = inc2;
    __syncthreads();
    if (tid < 4) {
        unsigned x = ws4[tid];
        #pragma unroll
        for (int d = 1; d < 4; d <<= 1) { unsigned t = __shfl_up(x, d); if (tid >= d) x += t; }
        ws4[tid] = x;
    }
    __syncthreads();
    unsigned exclB = inc2 - v2 + ((w == 0) ? 0u : ws4[w - 1]) + totA;
    o2[tid] = base + exclA;
    o2[tid + 256] = base + exclB;
    __syncthreads();
    int n0 = b * NBK + tid;
    int n1 = n0 + 256;
    if (n0 < N) off[n0] = o2[tid];
    if (n1 < N) off[n1] = o2[tid + 256];
    if (b == 0 && tid == 0) off[N] = (unsigned)E;
    __syncthreads();
    for (unsigned i = base + tid; i < end; i += 256) {
        u64 pk = tmp[i];
        unsigned dl  = (unsigned)(pk >> 51) & (NBK - 1);
        unsigned src = (unsigned)(pk >> 32) & 0x7FFFFu;
        unsigned vb  = (unsigned)pk;
        unsigned pos = atomicAdd(&o2[dl], 1u);  // LDS atomic
        fin[pos] = (u64)src | ((u64)vb << 32);
    }
}

// ---- concat(ue,ie) -> bf16 x0 (runs after p_bsort; x0 aliases tmp) ----
__global__ __launch_bounds__(BLK)
void k_cvt(const float* __restrict__ ue, const float* __restrict__ ie,
           u16* __restrict__ x0, long long u_elems, long long total4) {
    long long i = (long long)blockIdx.x * BLK + threadIdx.x;
    if (i >= total4) return;
    long long idx = i * 4;
    float4 b = (idx < u_elems) ? ldf4(ue + idx) : ldf4(ie + (idx - u_elems));
    ushort4 o;
    o.x = f2b(b.x); o.y = f2b(b.y); o.z = f2b(b.z); o.w = f2b(b.w);
    *reinterpret_cast<ushort4*>(x0 + idx) = o;
}

// ---- gather: one wave per dst node, 4 edges/iter (16 lanes x ushort4) ----
template<int FINAL>
__global__ __launch_bounds__(BLK)
void g_gather(const unsigned* __restrict__ off, const u64* __restrict__ edges,
              const u16* __restrict__ x, u16* __restrict__ hout,
              const float* __restrict__ ue, const float* __restrict__ ie,
              const u16* __restrict__ h1, const u16* __restrict__ h2,
              int n_users, float* __restrict__ out, int N) {
    __shared__ u64 sh[WPB][64];
    const int w    = threadIdx.x >> 6;
    const int lane = threadIdx.x & 63;
    const int node = blockIdx.x * WPB + w;
    if (node >= N) return;
    const int q  = lane >> 4;        // which edge within group of 4
    const int d4 = lane & 15;        // dims [4*d4 .. 4*d4+3]
    const unsigned beg = off[node];
    const unsigned end = off[node + 1];
    float4 a = {0.f, 0.f, 0.f, 0.f};
    for (unsigned base = beg; base < end; base += 64) {
        const int cnt = (int)min(64u, end - base);
        sh[w][lane] = (lane < cnt) ? edges[base + lane] : 0ull;  // pad src=0,val=0
        const int npad = (cnt + 3) & ~3;
        int j = 0;
        for (; j + 8 <= npad; j += 8) {
            u64 pa = sh[w][j + q];
            u64 pb = sh[w][j + 4 + q];
            unsigned sa = (unsigned)pa, sb = (unsigned)pb;
            float va = __uint_as_float((unsigned)(pa >> 32));
            float vb = __uint_as_float((unsigned)(pb >> 32));
            ushort4 xa = *reinterpret_cast<const ushort4*>(x + (size_t)sa * D + d4 * 4);
            ushort4 xb = *reinterpret_cast<const ushort4*>(x + (size_t)sb * D + d4 * 4);
            a.x += va * b2f(xa.x); a.y += va * b2f(xa.y);
            a.z += va * b2f(xa.z); a.w += va * b2f(xa.w);
            a.x += vb * b2f(xb.x); a.y += vb * b2f(xb.y);
            a.z += vb * b2f(xb.z); a.w += vb * b2f(xb.w);
        }
        for (; j < npad; j += 4) {
            u64 p = sh[w][j + q];
            unsigned s = (unsigned)p;
            float v = __uint_as_float((unsigned)(p >> 32));
            ushort4 xr = *reinterpret_cast<const ushort4*>(x + (size_t)s * D + d4 * 4);
            a.x += v * b2f(xr.x); a.y += v * b2f(xr.y);
            a.z += v * b2f(xr.z); a.w += v * b2f(xr.w);
        }
    }
    // reduce the 4 quarter-wave partials (lanes sharing d4)
    #pragma unroll
    for (int m = 16; m < 64; m <<= 1) {
        a.x += __shfl_xor(a.x, m);
        a.y += __shfl_xor(a.y, m);
        a.z += __shfl_xor(a.z, m);
        a.w += __shfl_xor(a.w, m);
    }
    if (lane < 16) {
        const size_t o = (size_t)node * D + (size_t)d4 * 4;
        if (FINAL) {
            const float* h0row = (node < n_users) ? (ue + (size_t)node * D)
                                                  : (ie + (size_t)(node - n_users) * D);
            float4 h0 = ldf4(h0row + d4 * 4);
            ushort4 r1 = *reinterpret_cast<const ushort4*>(h1 + o);
            ushort4 r2 = *reinterpret_cast<const ushort4*>(h2 + o);
            float4 r;
            r.x = (h0.x + b2f(r1.x) + b2f(r2.x) + a.x) * 0.25f;
            r.y = (h0.y + b2f(r1.y) + b2f(r2.y) + a.y) * 0.25f;
            r.z = (h0.z + b2f(r1.z) + b2f(r2.z) + a.z) * 0.25f;
            r.w = (h0.w + b2f(r1.w) + b2f(r2.w) + a.w) * 0.25f;
            *reinterpret_cast<float4*>(out + o) = r;
        } else {
            ushort4 hv;
            hv.x = f2b(a.x); hv.y = f2b(a.y); hv.z = f2b(a.z); hv.w = f2b(a.w);
            *reinterpret_cast<ushort4*>(hout + o) = hv;
        }
    }
}

// ---- fallback: atomic push path ----
__global__ __launch_bounds__(BLK)
void scatter_first(const int* __restrict__ esrc, const int* __restrict__ edst,
                   const float* __restrict__ ev,
                   const float* __restrict__ ue, const float* __restrict__ ie,
                   int n_users, float* __restrict__ y, int n_edges) {
    long long t = (long long)blockIdx.x * BLK + threadIdx.x;
    int e = (int)(t >> 4);
    if (e >= n_edges) return;
    int lane = (int)(threadIdx.x & 15);
    int s = esrc[e]; int d = edst[e]; float v = ev[e];
    const float* xrow = (s < n_users) ? (ue + (size_t)s * D)
                                      : (ie + (size_t)(s - n_users) * D);
    float4 xs = ldf4(xrow + lane * 4);
    float* yp = y + (size_t)d * D + lane * 4;
    unsafeAtomicAdd(yp + 0, v * xs.x);
    unsafeAtomicAdd(yp + 1, v * xs.y);
    unsafeAtomicAdd(yp + 2, v * xs.z);
    unsafeAtomicAdd(yp + 3, v * xs.w);
}

__global__ __launch_bounds__(BLK)
void scatter_gen(const int* __restrict__ esrc, const int* __restrict__ edst,
                 const float* __restrict__ ev, const float* __restrict__ x,
                 float* __restrict__ y, int n_edges) {
    long long t = (long long)blockIdx.x * BLK + threadIdx.x;
    int e = (int)(t >> 4);
    if (e >= n_edges) return;
    int lane = (int)(threadIdx.x & 15);
    int s = esrc[e]; int d = edst[e]; float v = ev[e];
    float4 xs = ldf4(x + (size_t)s * D + lane * 4);
    float* yp = y + (size_t)d * D + lane * 4;
    unsafeAtomicAdd(yp + 0, v * xs.x);
    unsafeAtomicAdd(yp + 1, v * xs.y);
    unsafeAtomicAdd(yp + 2, v * xs.z);
    unsafeAtomicAdd(yp + 3, v * xs.w);
}

__global__ __launch_bounds__(BLK)
void combine4(const float* __restrict__ ue, const float* __restrict__ ie,
              const float* __restrict__ h1, const float* __restrict__ h2,
              const float* __restrict__ h3, float* __restrict__ out,
              long long u_elems, long long total4) {
    long long i = (long long)blockIdx.x * BLK + threadIdx.x;
    if (i >= total4) return;
    long long idx = i * 4;
    float4 b  = (idx < u_elems) ? ldf4(ue + idx) : ldf4(ie + (idx - u_elems));
    float4 a1 = ldf4(h1 + idx);
    float4 a2 = ldf4(h2 + idx);
    float4 a3 = ldf4(h3 + idx);
    float4 r;
    r.x = (b.x + a1.x + a2.x + a3.x) * 0.25f;
    r.y = (b.y + a1.y + a2.y + a3.y) * 0.25f;
    r.z = (b.z + a1.z + a2.z + a3.z) * 0.25f;
    r.w = (b.w + a1.w + a2.w + a3.w) * 0.25f;
    *reinterpret_cast<float4*>(out + idx) = r;
}

// ---- launch ----
extern "C" void kernel_launch(void* const* d_in, const int* in_sizes, int n_in,
                              void* d_out, int out_size, void* d_ws, size_t ws_size,
                              hipStream_t stream) {
    const float* ue   = (const float*)d_in[0];
    const float* ie   = (const float*)d_in[1];
    const int*   esrc = (const int*)d_in[2];
    const int*   edst = (const int*)d_in[3];
    const float* ev   = (const float*)d_in[4];

    const int n_users = in_sizes[0] / D;
    const int n_items = in_sizes[1] / D;
    const int E       = in_sizes[2];
    const int N       = n_users + n_items;
    const long long elems = (long long)N * D;
    const size_t bufBytes = (size_t)elems * sizeof(float);

    const int NB     = (N + NBK - 1) / NBK;
    const int nchunk = (E + CHUNK - 1) / CHUNK;
    const int M      = NB * nchunk;
    const int nb1    = (M + 1023) / 1024;

    const long long total4  = elems / 4;
    const int vecBlocks     = (int)((total4 + BLK - 1) / BLK);
    const long long u_elems = (long long)n_users * D;
    const int gBlocks       = (N + WPB - 1) / WPB;
    float* out = (float*)d_out;

    // workspace: x0 (bf16) aliases tmp (tmp dead after p_bsort, x0 written after)
    const size_t tmpBytes = (size_t)E * 8;
    const size_t hbBytes  = (size_t)elems * 2;
    char* p = (char*)d_ws;
    u64* tmp = (u64*)p;  u16* x0 = (u16*)p;   p += (tmpBytes > hbBytes ? tmpBytes : hbBytes);
    u16*      h1b  = (u16*)p;                 p += hbBytes;
    u16*      h2b  = (u16*)p;                 p += hbBytes;
    u64*      fin  = (u64*)p;                 p += tmpBytes;
    unsigned* cnt  = (unsigned*)p;            p += (size_t)M * 4;
    unsigned* off  = (unsigned*)p;            p += ((size_t)N + 1) * 4;
    unsigned* bsum = (unsigned*)p;            p += (size_t)nb1 * 4;
    unsigned* bsumX= (unsigned*)p;            p += ((size_t)nb1 + 1) * 4;
    const size_t need = (size_t)(p - (char*)d_ws);

    if (ws_size >= need && NB <= MAXNB && N < (1 << 19)) {
        // CSR build (atomic-free)
        p_hist<<<nchunk, 256, 0, stream>>>(edst, cnt, E, NB, nchunk);
        p_reduce<<<nb1, 1024, 0, stream>>>(cnt, bsum, M);
        k_scan<<<1, 1024, 0, stream>>>(bsum, bsumX, nb1);
        p_scanapply<<<nb1, 1024, 0, stream>>>(cnt, bsumX, M);
        p_part<<<nchunk, 256, 0, stream>>>(esrc, edst, ev, cnt, tmp, E, NB, nchunk);
        p_bsort<<<NB, 256, 0, stream>>>(tmp, cnt, fin, off, E, N, NB, nchunk);
        // bf16 source + 3 gather layers (layer 3 fused with final average)
        k_cvt<<<vecBlocks, BLK, 0, stream>>>(ue, ie, x0, u_elems, total4);
        g_gather<0><<<gBlocks, BLK, 0, stream>>>(off, fin, x0, h1b, ue, ie,
                                                 nullptr, nullptr, n_users, nullptr, N);
        g_gather<0><<<gBlocks, BLK, 0, stream>>>(off, fin, h1b, h2b, ue, ie,
                                                 nullptr, nullptr, n_users, nullptr, N);
        g_gather<1><<<gBlocks, BLK, 0, stream>>>(off, fin, h2b, nullptr, ue, ie,
                                                 h1b, h2b, n_users, out, N);
    } else {
        // fallback: atomic push path (3 * bufBytes)
        float* h1 = (float*)d_ws;
        float* h2 = (float*)((char*)d_ws + bufBytes);
        float* h3 = (float*)((char*)d_ws + 2 * bufBytes);
        const int scatterBlocks = (int)(((long long)E * 16 + BLK - 1) / BLK);
        hipMemsetAsync(h1, 0, bufBytes, stream);
        hipMemsetAsync(h2, 0, bufBytes, stream);
        hipMemsetAsync(h3, 0, bufBytes, stream);
        scatter_first<<<scatterBlocks, BLK, 0, stream>>>(esrc, edst, ev, ue, ie,
                                                         n_users, h1, E);
        scatter_gen<<<scatterBlocks, BLK, 0, stream>>>(esrc, edst, ev, h1, h2, E);
        scatter_gen<<<scatterBlocks, BLK, 0, stream>>>(esrc, edst, ev, h2, h3, E);
        combine4<<<vecBlocks, BLK, 0, stream>>>(ue, ie, h1, h2, h3, out,
                                                u_elems, total4);
    }
}

// Round 7
// 952.019 us; speedup vs baseline: 25.6202x; 1.0496x over previous
//
#include <hip/hip_runtime.h>

// LightGCN on MI355X, round 7.
// CSR build (atomic-free two-level counting sort, 512-thread blocks) +
// bf16 features; gather = 8 lanes/edge, uint4 (16B) x-loads, unroll x4 MLP,
// nontemporal edge stream; layer 3 fused with final average.

static constexpr int D     = 64;
static constexpr int BLK   = 256;
static constexpr int WPB   = BLK / 64;   // nodes per gather block
static constexpr int CHUNK = 16384;      // edges per partition chunk
static constexpr int NBK   = 512;        // nodes per bucket (dst>>9)
static constexpr int MAXNB = 1024;

typedef unsigned long long u64;
typedef unsigned short u16;

__device__ __forceinline__ float4 ldf4(const float* p) {
    return *reinterpret_cast<const float4*>(p);
}
__device__ __forceinline__ u16 f2b(float f) {          // f32 -> bf16 (RNE)
    unsigned u = __float_as_uint(f);
    return (u16)((u + 0x7FFFu + ((u >> 16) & 1u)) >> 16);
}
__device__ __forceinline__ float b2f(u16 h) {
    return __uint_as_float((unsigned)h << 16);
}
__device__ __forceinline__ float blo(unsigned u) {     // low bf16 of a pair
    return __uint_as_float(u << 16);
}
__device__ __forceinline__ float bhi(unsigned u) {     // high bf16 of a pair
    return __uint_as_float(u & 0xFFFF0000u);
}

// ---- pass A: per-chunk histogram over coarse buckets ----
__global__ __launch_bounds__(512)
void p_hist(const int* __restrict__ edst, unsigned* __restrict__ cnt,
            int E, int NB, int nchunk) {
    __shared__ unsigned h[MAXNB];
    const int c = blockIdx.x;
    for (int j = threadIdx.x; j < NB; j += 512) h[j] = 0u;
    __syncthreads();
    const long long base = (long long)c * CHUNK;
    const int lim = (int)min((long long)CHUNK, (long long)E - base);
    const int nv = lim >> 2;
    const int4* d4 = (const int4*)(edst + base);
    for (int i = threadIdx.x; i < nv; i += 512) {
        int4 d = d4[i];
        atomicAdd(&h[(unsigned)d.x >> 9], 1u);
        atomicAdd(&h[(unsigned)d.y >> 9], 1u);
        atomicAdd(&h[(unsigned)d.z >> 9], 1u);
        atomicAdd(&h[(unsigned)d.w >> 9], 1u);
    }
    for (int i = (nv << 2) + threadIdx.x; i < lim; i += 512)
        atomicAdd(&h[(unsigned)edst[base + i] >> 9], 1u);
    __syncthreads();
    for (int j = threadIdx.x; j < NB; j += 512)
        cnt[(size_t)j * nchunk + c] = h[j];
}

// ---- scan pass 1: per-1024-block reduce ----
__global__ __launch_bounds__(1024)
void p_reduce(const unsigned* __restrict__ cnt, unsigned* __restrict__ bsum, int M) {
    __shared__ unsigned wsum[16];
    int i = blockIdx.x * 1024 + threadIdx.x;
    unsigned v = (i < M) ? cnt[i] : 0u;
    #pragma unroll
    for (int d = 1; d < 64; d <<= 1) v += __shfl_xor(v, d);
    if ((threadIdx.x & 63) == 0) wsum[threadIdx.x >> 6] = v;
    __syncthreads();
    if (threadIdx.x < 16) {
        unsigned x = wsum[threadIdx.x];
        #pragma unroll
        for (int d = 1; d < 16; d <<= 1) x += __shfl_xor(x, d);
        if (threadIdx.x == 0) bsum[blockIdx.x] = x;
    }
}

// ---- scan pass 2: single-block exclusive scan (small arrays) ----
__global__ __launch_bounds__(1024)
void k_scan(const unsigned* __restrict__ cnt, unsigned* __restrict__ off, int N) {
    __shared__ unsigned wsum[16];
    __shared__ unsigned carry_s;
    const int lane = threadIdx.x & 63;
    const int w    = threadIdx.x >> 6;
    if (threadIdx.x == 0) carry_s = 0;
    __syncthreads();
    for (int base = 0; base < N; base += 1024) {
        int i = base + (int)threadIdx.x;
        unsigned v = (i < N) ? cnt[i] : 0u;
        unsigned inc = v;
        #pragma unroll
        for (int d = 1; d < 64; d <<= 1) {
            unsigned t = __shfl_up(inc, d);
            if (lane >= d) inc += t;
        }
        if (lane == 63) wsum[w] = inc;
        __syncthreads();
        if (threadIdx.x < 16) {
            unsigned x = wsum[threadIdx.x];
            #pragma unroll
            for (int d = 1; d < 16; d <<= 1) {
                unsigned t = __shfl_up(x, d);
                if ((int)threadIdx.x >= d) x += t;
            }
            wsum[threadIdx.x] = x;
        }
        __syncthreads();
        unsigned carry = carry_s;
        unsigned woff  = (w == 0) ? 0u : wsum[w - 1];
        if (i < N) off[i] = carry + woff + inc - v;
        __syncthreads();
        if (threadIdx.x == 1023) carry_s = carry + wsum[15];
        __syncthreads();
    }
    if (threadIdx.x == 0) off[N] = carry_s;
}

// ---- scan pass 3: block exclusive scan + block base, in place ----
__global__ __launch_bounds__(1024)
void p_scanapply(unsigned* __restrict__ cnt, const unsigned* __restrict__ bsumX, int M) {
    __shared__ unsigned wsum[16];
    const int lane = threadIdx.x & 63;
    const int w    = threadIdx.x >> 6;
    int i = blockIdx.x * 1024 + threadIdx.x;
    unsigned v = (i < M) ? cnt[i] : 0u;
    unsigned inc = v;
    #pragma unroll
    for (int d = 1; d < 64; d <<= 1) {
        unsigned t = __shfl_up(inc, d);
        if (lane >= d) inc += t;
    }
    if (lane == 63) wsum[w] = inc;
    __syncthreads();
    if (threadIdx.x < 16) {
        unsigned x = wsum[threadIdx.x];
        #pragma unroll
        for (int d = 1; d < 16; d <<= 1) {
            unsigned t = __shfl_up(x, d);
            if ((int)threadIdx.x >= d) x += t;
        }
        wsum[threadIdx.x] = x;
    }
    __syncthreads();
    unsigned excl = inc - v + ((w == 0) ? 0u : wsum[w - 1]) + bsumX[blockIdx.x];
    if (i < M) cnt[i] = excl;
}

// ---- pass C: rank-scatter into coarse buckets (LDS cursors) ----
__device__ __forceinline__ void part1(unsigned s, unsigned d, float v,
                                      unsigned* cur, u64* __restrict__ tmp) {
    unsigned b  = d >> 9;
    unsigned dl = d & (NBK - 1);
    unsigned pos = atomicAdd(&cur[b], 1u);   // LDS atomic
    tmp[pos] = ((u64)((dl << 19) | s) << 32) | __float_as_uint(v);
}

__global__ __launch_bounds__(512)
void p_part(const int* __restrict__ esrc, const int* __restrict__ edst,
            const float* __restrict__ ev, const unsigned* __restrict__ cnt,
            u64* __restrict__ tmp, int E, int NB, int nchunk) {
    __shared__ unsigned cur[MAXNB];
    const int c = blockIdx.x;
    for (int j = threadIdx.x; j < NB; j += 512)
        cur[j] = cnt[(size_t)j * nchunk + c];
    __syncthreads();
    const long long base = (long long)c * CHUNK;
    const int lim = (int)min((long long)CHUNK, (long long)E - base);
    const int nv = lim >> 2;
    const int4*   s4 = (const int4*)(esrc + base);
    const int4*   d4 = (const int4*)(edst + base);
    const float4* v4 = (const float4*)(ev + base);
    for (int i = threadIdx.x; i < nv; i += 512) {
        int4 ss = s4[i]; int4 dd = d4[i]; float4 vv = v4[i];
        part1((unsigned)ss.x, (unsigned)dd.x, vv.x, cur, tmp);
        part1((unsigned)ss.y, (unsigned)dd.y, vv.y, cur, tmp);
        part1((unsigned)ss.z, (unsigned)dd.z, vv.z, cur, tmp);
        part1((unsigned)ss.w, (unsigned)dd.w, vv.w, cur, tmp);
    }
    for (int i = (nv << 2) + threadIdx.x; i < lim; i += 512)
        part1((unsigned)esrc[base + i], (unsigned)edst[base + i], ev[base + i], cur, tmp);
}

// ---- pass D: per-bucket LDS counting sort -> final edges + CSR off[] ----
__global__ __launch_bounds__(512)
void p_bsort(const u64* __restrict__ tmp, const unsigned* __restrict__ cnt,
             u64* __restrict__ fin, unsigned* __restrict__ off,
             int E, int N, int NB, int nchunk) {
    __shared__ unsigned c2[NBK];
    __shared__ unsigned o2[NBK];
    __shared__ unsigned ws8[8];
    const int b = blockIdx.x, tid = threadIdx.x;
    const int lane = tid & 63, w = tid >> 6;
    const unsigned base = cnt[(size_t)b * nchunk];
    const unsigned end  = (b + 1 < NB) ? cnt[(size_t)(b + 1) * nchunk] : (unsigned)E;
    c2[tid] = 0u;
    __syncthreads();
    for (unsigned i = base + tid; i < end; i += 512) {
        unsigned dl = (unsigned)(tmp[i] >> 51) & (NBK - 1);
        atomicAdd(&c2[dl], 1u);
    }
    __syncthreads();
    // single-pass exclusive scan of 512 counters (8 waves)
    unsigned v = c2[tid], inc = v;
    #pragma unroll
    for (int d = 1; d < 64; d <<= 1) { unsigned t = __shfl_up(inc, d); if (lane >= d) inc += t; }
    if (lane == 63) ws8[w] = inc;
    __syncthreads();
    if (tid < 8) {
        unsigned x = ws8[tid];
        #pragma unroll
        for (int d = 1; d < 8; d <<= 1) { unsigned t = __shfl_up(x, d); if (tid >= d) x += t; }
        ws8[tid] = x;
    }
    __syncthreads();
    const unsigned excl = inc - v + ((w == 0) ? 0u : ws8[w - 1]);
    const unsigned mybase = base + excl;
    o2[tid] = mybase;
    // CSR offsets (own-register value; no LDS dependency)
    int n0 = b * NBK + tid;
    if (n0 < N) off[n0] = mybase;
    if (b == 0 && tid == 0) off[N] = (unsigned)E;
    __syncthreads();
    for (unsigned i = base + tid; i < end; i += 512) {
        u64 pk = tmp[i];
        unsigned dl  = (unsigned)(pk >> 51) & (NBK - 1);
        unsigned src = (unsigned)(pk >> 32) & 0x7FFFFu;
        unsigned vb  = (unsigned)pk;
        unsigned pos = atomicAdd(&o2[dl], 1u);  // LDS atomic
        fin[pos] = (u64)src | ((u64)vb << 32);
    }
}

// ---- concat(ue,ie) -> bf16 x0 (runs after p_bsort; x0 aliases tmp) ----
__global__ __launch_bounds__(BLK)
void k_cvt(const float* __restrict__ ue, const float* __restrict__ ie,
           u16* __restrict__ x0, long long u_elems, long long total4) {
    long long i = (long long)blockIdx.x * BLK + threadIdx.x;
    if (i >= total4) return;
    long long idx = i * 4;
    float4 b = (idx < u_elems) ? ldf4(ue + idx) : ldf4(ie + (idx - u_elems));
    ushort4 o;
    o.x = f2b(b.x); o.y = f2b(b.y); o.z = f2b(b.z); o.w = f2b(b.w);
    *reinterpret_cast<ushort4*>(x0 + idx) = o;
}

// ---- gather: one wave per dst node, 8 lanes/edge, uint4 x-loads ----
template<int FINAL>
__global__ __launch_bounds__(BLK)
void g_gather(const unsigned* __restrict__ off, const u64* __restrict__ edges,
              const u16* __restrict__ x, u16* __restrict__ hout,
              const float* __restrict__ ue, const float* __restrict__ ie,
              const u16* __restrict__ h1, const u16* __restrict__ h2,
              int n_users, float* __restrict__ out, int N) {
    __shared__ u64 sh[WPB][64];
    const int w    = threadIdx.x >> 6;
    const int lane = threadIdx.x & 63;
    const int node = blockIdx.x * WPB + w;
    if (node >= N) return;
    const int q  = lane >> 3;        // edge slot within group of 8
    const int d8 = lane & 7;         // dims [8*d8, 8*d8+8)
    const unsigned beg = off[node];
    const unsigned end = off[node + 1];
    float a0=0.f,a1=0.f,a2=0.f,a3=0.f,a4=0.f,a5=0.f,a6=0.f,a7=0.f;
    for (unsigned base = beg; base < end; base += 64) {
        const int cnt = (int)min(64u, end - base);
        sh[w][lane] = (lane < cnt) ? __builtin_nontemporal_load(&edges[base + lane])
                                   : 0ull;                 // pad: src=0, val=0
        const int npad = (cnt + 7) & ~7;
        int j = 0;
        for (; j + 32 <= npad; j += 32) {
            u64 p0 = sh[w][j      + q];
            u64 p1 = sh[w][j +  8 + q];
            u64 p2 = sh[w][j + 16 + q];
            u64 p3 = sh[w][j + 24 + q];
            const uint4 x0v = *reinterpret_cast<const uint4*>(x + (size_t)(unsigned)p0 * D + d8 * 8);
            const uint4 x1v = *reinterpret_cast<const uint4*>(x + (size_t)(unsigned)p1 * D + d8 * 8);
            const uint4 x2v = *reinterpret_cast<const uint4*>(x + (size_t)(unsigned)p2 * D + d8 * 8);
            const uint4 x3v = *reinterpret_cast<const uint4*>(x + (size_t)(unsigned)p3 * D + d8 * 8);
            float v0 = __uint_as_float((unsigned)(p0 >> 32));
            float v1 = __uint_as_float((unsigned)(p1 >> 32));
            float v2 = __uint_as_float((unsigned)(p2 >> 32));
            float v3 = __uint_as_float((unsigned)(p3 >> 32));
            a0 += v0*blo(x0v.x); a1 += v0*bhi(x0v.x); a2 += v0*blo(x0v.y); a3 += v0*bhi(x0v.y);
            a4 += v0*blo(x0v.z); a5 += v0*bhi(x0v.z); a6 += v0*blo(x0v.w); a7 += v0*bhi(x0v.w);
            a0 += v1*blo(x1v.x); a1 += v1*bhi(x1v.x); a2 += v1*blo(x1v.y); a3 += v1*bhi(x1v.y);
            a4 += v1*blo(x1v.z); a5 += v1*bhi(x1v.z); a6 += v1*blo(x1v.w); a7 += v1*bhi(x1v.w);
            a0 += v2*blo(x2v.x); a1 += v2*bhi(x2v.x); a2 += v2*blo(x2v.y); a3 += v2*bhi(x2v.y);
            a4 += v2*blo(x2v.z); a5 += v2*bhi(x2v.z); a6 += v2*blo(x2v.w); a7 += v2*bhi(x2v.w);
            a0 += v3*blo(x3v.x); a1 += v3*bhi(x3v.x); a2 += v3*blo(x3v.y); a3 += v3*bhi(x3v.y);
            a4 += v3*blo(x3v.z); a5 += v3*bhi(x3v.z); a6 += v3*blo(x3v.w); a7 += v3*bhi(x3v.w);
        }
        for (; j < npad; j += 8) {
            u64 p = sh[w][j + q];
            const uint4 xv = *reinterpret_cast<const uint4*>(x + (size_t)(unsigned)p * D + d8 * 8);
            float v = __uint_as_float((unsigned)(p >> 32));
            a0 += v*blo(xv.x); a1 += v*bhi(xv.x); a2 += v*blo(xv.y); a3 += v*bhi(xv.y);
            a4 += v*blo(xv.z); a5 += v*bhi(xv.z); a6 += v*blo(xv.w); a7 += v*bhi(xv.w);
        }
    }
    // reduce across the 8 edge-slots (lanes sharing d8)
    #pragma unroll
    for (int m = 8; m < 64; m <<= 1) {
        a0 += __shfl_xor(a0, m); a1 += __shfl_xor(a1, m);
        a2 += __shfl_xor(a2, m); a3 += __shfl_xor(a3, m);
        a4 += __shfl_xor(a4, m); a5 += __shfl_xor(a5, m);
        a6 += __shfl_xor(a6, m); a7 += __shfl_xor(a7, m);
    }
    if (lane < 8) {
        const size_t o = (size_t)node * D + (size_t)d8 * 8;
        if (FINAL) {
            const float* h0row = (node < n_users) ? (ue + (size_t)node * D)
                                                  : (ie + (size_t)(node - n_users) * D);
            float4 hA = ldf4(h0row + d8 * 8);
            float4 hB = ldf4(h0row + d8 * 8 + 4);
            uint4 r1 = *reinterpret_cast<const uint4*>(h1 + o);
            uint4 r2 = *reinterpret_cast<const uint4*>(h2 + o);
            float4 oA, oB;
            oA.x = (hA.x + blo(r1.x) + blo(r2.x) + a0) * 0.25f;
            oA.y = (hA.y + bhi(r1.x) + bhi(r2.x) + a1) * 0.25f;
            oA.z = (hA.z + blo(r1.y) + blo(r2.y) + a2) * 0.25f;
            oA.w = (hA.w + bhi(r1.y) + bhi(r2.y) + a3) * 0.25f;
            oB.x = (hB.x + blo(r1.z) + blo(r2.z) + a4) * 0.25f;
            oB.y = (hB.y + bhi(r1.z) + bhi(r2.z) + a5) * 0.25f;
            oB.z = (hB.z + blo(r1.w) + blo(r2.w) + a6) * 0.25f;
            oB.w = (hB.w + bhi(r1.w) + bhi(r2.w) + a7) * 0.25f;
            *reinterpret_cast<float4*>(out + o)     = oA;
            *reinterpret_cast<float4*>(out + o + 4) = oB;
        } else {
            uint4 hv;
            hv.x = ((unsigned)f2b(a1) << 16) | f2b(a0);
            hv.y = ((unsigned)f2b(a3) << 16) | f2b(a2);
            hv.z = ((unsigned)f2b(a5) << 16) | f2b(a4);
            hv.w = ((unsigned)f2b(a7) << 16) | f2b(a6);
            *reinterpret_cast<uint4*>(hout + o) = hv;
        }
    }
}

// ---- fallback: atomic push path ----
__global__ __launch_bounds__(BLK)
void scatter_first(const int* __restrict__ esrc, const int* __restrict__ edst,
                   const float* __restrict__ ev,
                   const float* __restrict__ ue, const float* __restrict__ ie,
                   int n_users, float* __restrict__ y, int n_edges) {
    long long t = (long long)blockIdx.x * BLK + threadIdx.x;
    int e = (int)(t >> 4);
    if (e >= n_edges) return;
    int lane = (int)(threadIdx.x & 15);
    int s = esrc[e]; int d = edst[e]; float v = ev[e];
    const float* xrow = (s < n_users) ? (ue + (size_t)s * D)
                                      : (ie + (size_t)(s - n_users) * D);
    float4 xs = ldf4(xrow + lane * 4);
    float* yp = y + (size_t)d * D + lane * 4;
    unsafeAtomicAdd(yp + 0, v * xs.x);
    unsafeAtomicAdd(yp + 1, v * xs.y);
    unsafeAtomicAdd(yp + 2, v * xs.z);
    unsafeAtomicAdd(yp + 3, v * xs.w);
}

__global__ __launch_bounds__(BLK)
void scatter_gen(const int* __restrict__ esrc, const int* __restrict__ edst,
                 const float* __restrict__ ev, const float* __restrict__ x,
                 float* __restrict__ y, int n_edges) {
    long long t = (long long)blockIdx.x * BLK + threadIdx.x;
    int e = (int)(t >> 4);
    if (e >= n_edges) return;
    int lane = (int)(threadIdx.x & 15);
    int s = esrc[e]; int d = edst[e]; float v = ev[e];
    float4 xs = ldf4(x + (size_t)s * D + lane * 4);
    float* yp = y + (size_t)d * D + lane * 4;
    unsafeAtomicAdd(yp + 0, v * xs.x);
    unsafeAtomicAdd(yp + 1, v * xs.y);
    unsafeAtomicAdd(yp + 2, v * xs.z);
    unsafeAtomicAdd(yp + 3, v * xs.w);
}

__global__ __launch_bounds__(BLK)
void combine4(const float* __restrict__ ue, const float* __restrict__ ie,
              const float* __restrict__ h1, const float* __restrict__ h2,
              const float* __restrict__ h3, float* __restrict__ out,
              long long u_elems, long long total4) {
    long long i = (long long)blockIdx.x * BLK + threadIdx.x;
    if (i >= total4) return;
    long long idx = i * 4;
    float4 b  = (idx < u_elems) ? ldf4(ue + idx) : ldf4(ie + (idx - u_elems));
    float4 a1 = ldf4(h1 + idx);
    float4 a2 = ldf4(h2 + idx);
    float4 a3 = ldf4(h3 + idx);
    float4 r;
    r.x = (b.x + a1.x + a2.x + a3.x) * 0.25f;
    r.y = (b.y + a1.y + a2.y + a3.y) * 0.25f;
    r.z = (b.z + a1.z + a2.z + a3.z) * 0.25f;
    r.w = (b.w + a1.w + a2.w + a3.w) * 0.25f;
    *reinterpret_cast<float4*>(out + idx) = r;
}

// ---- launch ----
extern "C" void kernel_launch(void* const* d_in, const int* in_sizes, int n_in,
                              void* d_out, int out_size, void* d_ws, size_t ws_size,
                              hipStream_t stream) {
    const float* ue   = (const float*)d_in[0];
    const float* ie   = (const float*)d_in[1];
    const int*   esrc = (const int*)d_in[2];
    const int*   edst = (const int*)d_in[3];
    const float* ev   = (const float*)d_in[4];

    const int n_users = in_sizes[0] / D;
    const int n_items = in_sizes[1] / D;
    const int E       = in_sizes[2];
    const int N       = n_users + n_items;
    const long long elems = (long long)N * D;
    const size_t bufBytes = (size_t)elems * sizeof(float);

    const int NB     = (N + NBK - 1) / NBK;
    const int nchunk = (E + CHUNK - 1) / CHUNK;
    const int M      = NB * nchunk;
    const int nb1    = (M + 1023) / 1024;

    const long long total4  = elems / 4;
    const int vecBlocks     = (int)((total4 + BLK - 1) / BLK);
    const long long u_elems = (long long)n_users * D;
    const int gBlocks       = (N + WPB - 1) / WPB;
    float* out = (float*)d_out;

    // workspace: x0 (bf16) aliases tmp (tmp dead after p_bsort, x0 written after)
    const size_t tmpBytes = (size_t)E * 8;
    const size_t hbBytes  = (size_t)elems * 2;
    char* p = (char*)d_ws;
    u64* tmp = (u64*)p;  u16* x0 = (u16*)p;   p += (tmpBytes > hbBytes ? tmpBytes : hbBytes);
    u16*      h1b  = (u16*)p;                 p += hbBytes;
    u16*      h2b  = (u16*)p;                 p += hbBytes;
    u64*      fin  = (u64*)p;                 p += tmpBytes;
    unsigned* cnt  = (unsigned*)p;            p += (size_t)M * 4;
    unsigned* off  = (unsigned*)p;            p += ((size_t)N + 1) * 4;
    unsigned* bsum = (unsigned*)p;            p += (size_t)nb1 * 4;
    unsigned* bsumX= (unsigned*)p;            p += ((size_t)nb1 + 1) * 4;
    const size_t need = (size_t)(p - (char*)d_ws);

    if (ws_size >= need && NB <= MAXNB && N < (1 << 19)) {
        // CSR build (atomic-free)
        p_hist<<<nchunk, 512, 0, stream>>>(edst, cnt, E, NB, nchunk);
        p_reduce<<<nb1, 1024, 0, stream>>>(cnt, bsum, M);
        k_scan<<<1, 1024, 0, stream>>>(bsum, bsumX, nb1);
        p_scanapply<<<nb1, 1024, 0, stream>>>(cnt, bsumX, M);
        p_part<<<nchunk, 512, 0, stream>>>(esrc, edst, ev, cnt, tmp, E, NB, nchunk);
        p_bsort<<<NB, 512, 0, stream>>>(tmp, cnt, fin, off, E, N, NB, nchunk);
        // bf16 source + 3 gather layers (layer 3 fused with final average)
        k_cvt<<<vecBlocks, BLK, 0, stream>>>(ue, ie, x0, u_elems, total4);
        g_gather<0><<<gBlocks, BLK, 0, stream>>>(off, fin, x0, h1b, ue, ie,
                                                 nullptr, nullptr, n_users, nullptr, N);
        g_gather<0><<<gBlocks, BLK, 0, stream>>>(off, fin, h1b, h2b, ue, ie,
                                                 nullptr, nullptr, n_users, nullptr, N);
        g_gather<1><<<gBlocks, BLK, 0, stream>>>(off, fin, h2b, nullptr, ue, ie,
                                                 h1b, h2b, n_users, out, N);
    } else {
        // fallback: atomic push path (3 * bufBytes)
        float* h1 = (float*)d_ws;
        float* h2 = (float*)((char*)d_ws + bufBytes);
        float* h3 = (float*)((char*)d_ws + 2 * bufBytes);
        const int scatterBlocks = (int)(((long long)E * 16 + BLK - 1) / BLK);
        hipMemsetAsync(h1, 0, bufBytes, stream);
        hipMemsetAsync(h2, 0, bufBytes, stream);
        hipMemsetAsync(h3, 0, bufBytes, stream);
        scatter_first<<<scatterBlocks, BLK, 0, stream>>>(esrc, edst, ev, ue, ie,
                                                         n_users, h1, E);
        scatter_gen<<<scatterBlocks, BLK, 0, stream>>>(esrc, edst, ev, h1, h2, E);
        scatter_gen<<<scatterBlocks, BLK, 0, stream>>>(esrc, edst, ev, h2, h3, E);
        combine4<<<vecBlocks, BLK, 0, stream>>>(ue, ie, h1, h2, h3, out,
                                                u_elems, total4);
    }
}